// Round 7
// baseline (43.110 us; speedup 1.0000x reference)
//
#include <hip/hip_runtime.h>

// B=32, H=W=512, C=3, toroidal 3x3 uniform depthwise avg + per-pixel quadratic forms.
#define HH 512
#define ROW4 384            // float4 per image row (512*3/4)
#define RPW 2               // output rows per wave (max TLP + full load ILP)
#define EPS 0.1f

__global__ __launch_bounds__(256)
void gnllt_kernel(const float* __restrict__ xin,
                  const float* __restrict__ A,
                  const float* __restrict__ Bm,
                  const float* __restrict__ Cm,
                  const float* __restrict__ bias,
                  const float* __restrict__ wk,
                  float* __restrict__ outp)
{
    const int lane  = threadIdx.x & 63;
    const int wid   = (blockIdx.x << 2) | (threadIdx.x >> 6);
    const int strip = wid & 1;            // two 256-px strips per row
    const int grp   = wid >> 1;           // 0..8191
    const int img   = grp >> 8;           // 0..31 (256 row-groups per image)
    const int h0    = (grp & 255) * RPW;  // 0..510

    // Uniform parameter loads -> SGPRs. Fold eps*wv^2 into quad coeffs, eps into bias.
    const float wv = wk[0];
    const float qs = EPS * wv * wv;
    const float qa00 = qs*A[0],  qa11 = qs*A[4],  qa22 = qs*A[8];
    const float qa01 = qs*(A[1]+A[3]),  qa02 = qs*(A[2]+A[6]),  qa12 = qs*(A[5]+A[7]);
    const float qb00 = qs*Bm[0], qb11 = qs*Bm[4], qb22 = qs*Bm[8];
    const float qb01 = qs*(Bm[1]+Bm[3]), qb02 = qs*(Bm[2]+Bm[6]), qb12 = qs*(Bm[5]+Bm[7]);
    const float qc00 = qs*Cm[0], qc11 = qs*Cm[4], qc22 = qs*Cm[8];
    const float qc01 = qs*(Cm[1]+Cm[3]), qc02 = qs*(Cm[2]+Cm[6]), qc12 = qs*(Cm[5]+Cm[7]);
    const float bi0 = EPS*bias[0], bi1 = EPS*bias[1], bi2 = EPS*bias[2];

    const float4* x4 = (const float4*)xin;
    float4*       o4 = (float4*)outp;

    // f4-column indices for the 5 overlapping loads (explicit wrap; 384 not pow2)
    const int cb = strip * 192 + 3 * lane;     // first own f4 in row
    int c[5];
    #pragma unroll
    for (int j = 0; j < 5; ++j) {
        int v = cb - 1 + j;
        if (v < 0)     v += ROW4;
        if (v >= ROW4) v -= ROW4;
        c[j] = v;
    }
    const size_t ib = (size_t)img * (HH * ROW4);

    // ---- Load all 4 rows (h0-1, h0, h0+1, h0+2), 20 independent float4 loads ----
    float4 F[4][5];
    #pragma unroll
    for (int r = 0; r < 4; ++r) {
        const int hr = (h0 - 1 + r + HH) & (HH - 1);
        const float4* rp = x4 + ib + (size_t)hr * ROW4;
        #pragma unroll
        for (int j = 0; j < 5; ++j) F[r][j] = rp[c[j]];
    }

    // ---- Horizontal channel-sums per row: hs[r][3j+c] over px-1..px+1 ----
    float hs[4][12];
    float raw[2][12];
    #pragma unroll
    for (int r = 0; r < 4; ++r) {
        float g[20] = {F[r][0].x,F[r][0].y,F[r][0].z,F[r][0].w,
                       F[r][1].x,F[r][1].y,F[r][1].z,F[r][1].w,
                       F[r][2].x,F[r][2].y,F[r][2].z,F[r][2].w,
                       F[r][3].x,F[r][3].y,F[r][3].z,F[r][3].w,
                       F[r][4].x,F[r][4].y,F[r][4].z,F[r][4].w};
        #pragma unroll
        for (int q = 0; q < 12; ++q) hs[r][q] = g[1+q] + g[4+q] + g[7+q];
        if (r == 1 || r == 2) {
            #pragma unroll
            for (int q = 0; q < 12; ++q) raw[r-1][q] = g[4+q];
        }
    }

    // ---- Two output rows ----
    #pragma unroll
    for (int i = 0; i < RPW; ++i) {
        const float* hm  = hs[i];
        const float* hc  = hs[i + 1];
        const float* hp  = hs[i + 2];
        const float* rw  = raw[i];

        float of[12];
        #pragma unroll
        for (int j = 0; j < 4; ++j) {
            const float s0 = hm[3*j+0] + hc[3*j+0] + hp[3*j+0];
            const float s1 = hm[3*j+1] + hc[3*j+1] + hp[3*j+1];
            const float s2 = hm[3*j+2] + hc[3*j+2] + hp[3*j+2];
            const float p00 = s0*s0, p11 = s1*s1, p22 = s2*s2;
            const float p01 = s0*s1, p02 = s0*s2, p12 = s1*s2;
            of[3*j+0] = rw[3*j+0] + bi0 + qa00*p00 + qa11*p11 + qa22*p22
                                        + qa01*p01 + qa02*p02 + qa12*p12;
            of[3*j+1] = rw[3*j+1] + bi1 + qb00*p00 + qb11*p11 + qb22*p22
                                        + qb01*p01 + qb02*p02 + qb12*p12;
            of[3*j+2] = rw[3*j+2] + bi2 + qc00*p00 + qc11*p11 + qc22*p22
                                        + qc01*p01 + qc02*p02 + qc12*p12;
        }

        float4* op = o4 + ib + (size_t)(h0 + i) * ROW4 + cb;
        op[0] = make_float4(of[0], of[1], of[2],  of[3]);
        op[1] = make_float4(of[4], of[5], of[6],  of[7]);
        op[2] = make_float4(of[8], of[9], of[10], of[11]);
    }
}

extern "C" void kernel_launch(void* const* d_in, const int* in_sizes, int n_in,
                              void* d_out, int out_size, void* d_ws, size_t ws_size,
                              hipStream_t stream) {
    const float* x    = (const float*)d_in[0];
    const float* A    = (const float*)d_in[1];
    const float* Bm   = (const float*)d_in[2];
    const float* Cm   = (const float*)d_in[3];
    const float* bias = (const float*)d_in[4];
    const float* wk   = (const float*)d_in[5];
    float* out = (float*)d_out;

    // 32 imgs x 256 row-groups x 2 strips = 16384 waves = 4096 blocks of 4 waves
    dim3 grid(4096);
    dim3 block(256);
    gnllt_kernel<<<grid, block, 0, stream>>>(x, A, Bm, Cm, bias, wk, out);
}